// Round 17
// baseline (384.786 us; speedup 1.0000x reference)
//
#include <hip/hip_runtime.h>

typedef unsigned short u16;
typedef unsigned int u32;
typedef __attribute__((ext_vector_type(8))) short short8;
typedef __attribute__((ext_vector_type(4))) u16 u16x4;
typedef __attribute__((ext_vector_type(8))) u16 u16x8;
typedef __attribute__((ext_vector_type(2))) u32 u32x2;
typedef __attribute__((ext_vector_type(4))) float f32x4;

__device__ __forceinline__ u16 f2bf(float f) {
  unsigned u = __float_as_uint(f);
  u += 0x7fffu + ((u >> 16) & 1u);
  return (u16)(u >> 16);
}
__device__ __forceinline__ float b2f(u16 v) { return __uint_as_float((u32)v << 16); }

// async global->LDS DMA, 16B per lane, linear dest (wave-uniform base + lane*16)
#define GLD16(g, l)                                                        \
  __builtin_amdgcn_global_load_lds(                                        \
      (const __attribute__((address_space(1))) void*)(g),                  \
      (__attribute__((address_space(3))) void*)(l), 16, 0, 0)

// ---------------- merged weight transpose+cast: 7 jobs in one launch
struct TJobs {
  const float* in[7];
  unsigned long long outoff[7];  // byte offset into ws
  int ld[7], row0[7], K[7], blkend[7];
};
__global__ void transpose_all_kernel(TJobs J, char* __restrict__ ws) {
  int bx = blockIdx.x;
  int ji = 0;
  while (bx >= J.blkend[ji]) ji++;
  int base = (ji == 0) ? 0 : J.blkend[ji - 1];
  int i = (bx - base) * 256 + threadIdx.x;
  int K = J.K[ji];
  int j = i / K, k = i - j * K;
  u16* out = (u16*)(ws + J.outoff[ji]);
  out[(size_t)j * K + k] = f2bf(J.in[ji][(size_t)(J.row0[ji] + k) * J.ld[ji] + j]);
}

// ---------------- LayerNorm: 1 wave per row of 384, 6 elems/lane
__global__ void ln_kernel(const float* __restrict__ in, const float* __restrict__ w,
                          const float* __restrict__ b, u16* __restrict__ out) {
  int row = blockIdx.x, t = threadIdx.x;
  const float* r = in + (size_t)row * 384;
  float v[6];
  float s = 0.f;
#pragma unroll
  for (int i = 0; i < 6; i++) { v[i] = r[t + 64 * i]; s += v[i]; }
#pragma unroll
  for (int off = 32; off > 0; off >>= 1) s += __shfl_xor(s, off);
  float mu = s * (1.f / 384.f);
  float q = 0.f;
#pragma unroll
  for (int i = 0; i < 6; i++) { float d = v[i] - mu; q += d * d; }
#pragma unroll
  for (int off = 32; off > 0; off >>= 1) q += __shfl_xor(q, off);
  float rstd = rsqrtf(q * (1.f / 384.f) + 1e-5f);
#pragma unroll
  for (int i = 0; i < 6; i++) {
    int j = t + 64 * i;
    out[(size_t)row * 384 + j] = f2bf((v[i] - mu) * rstd * w[j] + b[j]);
  }
}

// ---------------- bf16 MFMA GEMM: C[M,N] = A[M,K] * Bt[N,K]^T
// 128xTN tile, 256 thr (4 waves 2x2). BK=64 as two stacked [rows][32] half-tiles
// (m97's proven 64B-stride LDS layout; halves barrier drains per FLOP).
// MODE 1: bf16 out + bias (strided ldc)
// MODE 2: merged qkv+GH split: q(scaled)|k -> [t,384]; vT -> [b][h][d][n]; GH bf16 [t,768]
// MODE 3: f32 out = acc + bias + res   MODE 4: bf16 out = gelu(acc+bias), tanh-form
template <int MODE, int TN>
__global__ __launch_bounds__(256) void gemm_kernel(
    const u16* __restrict__ A, const u16* __restrict__ Bt,
    int M, int N, int K, int ldc,
    const float* __restrict__ bias, const float* __restrict__ res,
    void* __restrict__ out0, void* __restrict__ out1, void* __restrict__ out2,
    void* __restrict__ out3) {
  __shared__ u16 Als[2][128 * 32];
  __shared__ u16 Bls[2][TN * 32];
  const int NJ = TN / 32;  // N-frags per wave
  const int MB = M >> 7;
  int mb = blockIdx.x % MB, nb = blockIdx.x / MB;
  int m0 = mb << 7, n0 = nb * TN;
  int tid = threadIdx.x;
  int lane = tid & 63, w = tid >> 6;
  int wm = (w >> 1) << 6, wn = (w & 1) * (TN / 2);
  int l15 = lane & 15, l16 = lane >> 4;
  const f32x4 fz = {0.f, 0.f, 0.f, 0.f};
  f32x4 acc[4][NJ];
#pragma unroll
  for (int i = 0; i < 4; i++)
#pragma unroll
    for (int j = 0; j < NJ; j++) acc[i][j] = fz;

  // staging: lane l -> row +(l>>2), chunk (l&3)*8; one GLD16 covers 16 rows
  const int strow = lane >> 2, stch = (lane & 3) * 8;
  const u16* Ag = A + (size_t)(m0 + w * 32 + strow) * K + stch;
  const u16* Bg = Bt + (size_t)(n0 + w * (TN / 4) + strow) * K + stch;
  u16* Al0 = &Als[0][(w * 32) * 32];
  u16* Al1 = &Als[1][(w * 32) * 32];
  u16* Bl0 = &Bls[0][(w * (TN / 4)) * 32];
  u16* Bl1 = &Bls[1][(w * (TN / 4)) * 32];

  for (int k0 = 0; k0 < K; k0 += 64) {
    __syncthreads();  // prev tile's ds_reads done
    GLD16(Ag + k0, Al0);
    GLD16(Ag + k0 + (size_t)16 * K, Al0 + 16 * 32);
    GLD16(Ag + k0 + 32, Al1);
    GLD16(Ag + k0 + 32 + (size_t)16 * K, Al1 + 16 * 32);
    GLD16(Bg + k0, Bl0);
    GLD16(Bg + k0 + 32, Bl1);
    if (TN == 128) {
      GLD16(Bg + k0 + (size_t)16 * K, Bl0 + 16 * 32);
      GLD16(Bg + k0 + 32 + (size_t)16 * K, Bl1 + 16 * 32);
    }
    asm volatile("s_waitcnt vmcnt(0)" ::: "memory");  // drain LDS-DMA before barrier
    __syncthreads();
#pragma unroll
    for (int kk = 0; kk < 2; kk++) {
      short8 af[4], bfr[NJ];
#pragma unroll
      for (int i = 0; i < 4; i++)
        af[i] = *(const short8*)&Als[kk][(wm + i * 16 + l15) * 32 + l16 * 8];
#pragma unroll
      for (int j = 0; j < NJ; j++)
        bfr[j] = *(const short8*)&Bls[kk][(wn + j * 16 + l15) * 32 + l16 * 8];
      __builtin_amdgcn_s_setprio(1);
#pragma unroll
      for (int i = 0; i < 4; i++)
#pragma unroll
        for (int j = 0; j < NJ; j++)
          acc[i][j] = __builtin_amdgcn_mfma_f32_16x16x32_bf16(af[i], bfr[j], acc[i][j], 0, 0, 0);
      __builtin_amdgcn_s_setprio(0);
    }
  }

#pragma unroll
  for (int i = 0; i < 4; i++)
#pragma unroll
    for (int j = 0; j < NJ; j++)
#pragma unroll
      for (int r = 0; r < 4; r++) {
        int row = m0 + wm + i * 16 + l16 * 4 + r;
        int col = n0 + wn + j * 16 + l15;
        float v = acc[i][j][r];
        if (MODE == 1) {
          ((u16*)out0)[(size_t)row * ldc + col] = f2bf(v + bias[col]);
        } else if (MODE == 2) {
          if (col < 384) {
            ((u16*)out0)[(size_t)row * 384 + col] = f2bf(v * 0.18033688011112042f);
          } else if (col < 768) {
            ((u16*)out1)[(size_t)row * 384 + col - 384] = f2bf(v);
          } else if (col < 1152) {
            int df = col - 768, hh = df >> 6, dd = df & 63;
            ((u16*)out2)[(((size_t)(row >> 11) * 6 + hh) * 64 + dd) * 2048 + (row & 2047)] = f2bf(v);
          } else {
            ((u16*)out3)[(size_t)row * 768 + (col - 1152)] = f2bf(v);
          }
        } else if (MODE == 3) {
          ((float*)out0)[(size_t)row * ldc + col] = v + bias[col] + res[(size_t)row * ldc + col];
        } else if (MODE == 4) {
          float u = v + bias[col];
          // tanh-form GELU via exp2 (max dev from erf-GELU ~3e-4, threshold 0.115)
          float t = u * (0.79788456f + 0.03567741f * u * u);
          float g = u / (1.f + exp2f(-2.88539008f * t));
          ((u16*)out0)[(size_t)row * ldc + col] = f2bf(g);
        }
      }
}

// ---------------- flash attention v8: K-fragments DIRECT FROM GLOBAL (L2-resident,
// offloads the LDS pipe which was the bottleneck: ~202k of 216k cyc/CU were LDS-issue).
// V+P stay in LDS. 8-wave blocks (128 q-rows), stride-80 rows, shift-free softmax,
// row-sum via ones-MFMA. grid = B*H*(N/128) = 768 = 3 blocks/CU.
#define ASTR 80  // LDS row stride in u16 (160 B): 4-way max read conflicts, 16B-aligned
__global__ __launch_bounds__(512) void attn_kernel(const u16* __restrict__ qb,
                                                   const u16* __restrict__ kb,
                                                   const u16* __restrict__ vtb,
                                                   u16* __restrict__ ab) {
  __shared__ u16 Vls[64 * ASTR];    // [d][j] (V pre-transposed in global)
  __shared__ u16 Pls[128 * ASTR];   // Q staging (128 rows), then P[q][key] per-wave rows
  int bx = blockIdx.x;
  int q0 = (bx & 15) << 7;
  int h = (bx >> 4) % 6;
  int b = bx / 96;
  int tid = threadIdx.x, lane = tid & 63, w = tid >> 6;  // w in 0..7
  int l15 = lane & 15, l16 = lane >> 4;

  // stage Q (128 rows x 64 cols) into Pls; each wave then reads only its own 16 rows
  const size_t qbase = (size_t)(b * 2048 + q0) * 384 + h * 64;
  {
    int i0 = tid, i1 = 512 + tid;
    *(short8*)&Pls[(i0 >> 3) * ASTR + (i0 & 7) * 8] =
        *(const short8*)&qb[qbase + (size_t)(i0 >> 3) * 384 + (i0 & 7) * 8];
    *(short8*)&Pls[(i1 >> 3) * ASTR + (i1 & 7) * 8] =
        *(const short8*)&qb[qbase + (size_t)(i1 >> 3) * 384 + (i1 & 7) * 8];
  }
  __syncthreads();
  short8 aq0 = *(const short8*)&Pls[(w * 16 + l15) * ASTR + l16 * 8];
  short8 aq1 = *(const short8*)&Pls[(w * 16 + l15) * ASTR + 32 + l16 * 8];

  const f32x4 fz = {0.f, 0.f, 0.f, 0.f};
  f32x4 ot[4];   // O^T: lane q = l15; d = di*16 + l16*4 + r
  f32x4 osum;    // P row-sum via ones-MFMA; every element = full sum for q=l15
#pragma unroll
  for (int di = 0; di < 4; di++) ot[di] = fz;
  osum = fz;
  short8 ones8;  // constant all-ones bf16 A-fragment (1.0 = 0x3F80)
#pragma unroll
  for (int i = 0; i < 8; i++) ones8[i] = (short)0x3F80;

  const size_t kbase = (size_t)b * 2048 * 384 + h * 64;
  const size_t vbase = ((size_t)b * 6 + h) * 64 * 2048;
  // per-lane K-fragment pointers (row = nj*16+l15, d-chunk = l16*8); stepped by tile
  const u16* kg0 = kb + kbase + (size_t)(0 * 16 + l15) * 384 + l16 * 8;
  const u16* kg1 = kb + kbase + (size_t)(1 * 16 + l15) * 384 + l16 * 8;
  const u16* kg2 = kb + kbase + (size_t)(2 * 16 + l15) * 384 + l16 * 8;
  const u16* kg3 = kb + kbase + (size_t)(3 * 16 + l15) * 384 + l16 * 8;

  // V staging: 64 rows x 64 cols = 512 short8 slots; 512 threads -> 1 slot each
  const int srow = tid >> 3, sch = (tid & 7) * 8;
  short8 vr = *(const short8*)&vtb[vbase + (size_t)srow * 2048 + sch];

  for (int t = 0; t < 32; t++) {
    const size_t toff = (size_t)t * 64 * 384;
    // issue this tile's K-fragment loads (global, L2-hit; land during barrier+staging)
    short8 kf00 = *(const short8*)&kg0[toff];
    short8 kf01 = *(const short8*)&kg0[toff + 32];
    short8 kf10 = *(const short8*)&kg1[toff];
    short8 kf11 = *(const short8*)&kg1[toff + 32];
    short8 kf20 = *(const short8*)&kg2[toff];
    short8 kf21 = *(const short8*)&kg2[toff + 32];
    short8 kf30 = *(const short8*)&kg3[toff];
    short8 kf31 = *(const short8*)&kg3[toff + 32];

    __syncthreads();  // previous tile's LDS reads done (and Q-staging consumed)
    *(short8*)&Vls[srow * ASTR + sch] = vr;
    if (t + 1 < 32) {  // issue next V tile's load; flies during compute below
      vr = *(const short8*)&vtb[vbase + (size_t)srow * 2048 + ((t + 1) << 6) + sch];
    }
    __syncthreads();

    // S^T = K·Q^T : mfma(A=K_frag(global), B=Q_frag) -> col=q=l15, row=key
    f32x4 s[4];
    __builtin_amdgcn_s_setprio(1);
    s[0] = __builtin_amdgcn_mfma_f32_16x16x32_bf16(kf00, aq0, fz, 0, 0, 0);
    s[0] = __builtin_amdgcn_mfma_f32_16x16x32_bf16(kf01, aq1, s[0], 0, 0, 0);
    s[1] = __builtin_amdgcn_mfma_f32_16x16x32_bf16(kf10, aq0, fz, 0, 0, 0);
    s[1] = __builtin_amdgcn_mfma_f32_16x16x32_bf16(kf11, aq1, s[1], 0, 0, 0);
    s[2] = __builtin_amdgcn_mfma_f32_16x16x32_bf16(kf20, aq0, fz, 0, 0, 0);
    s[2] = __builtin_amdgcn_mfma_f32_16x16x32_bf16(kf21, aq1, s[2], 0, 0, 0);
    s[3] = __builtin_amdgcn_mfma_f32_16x16x32_bf16(kf30, aq0, fz, 0, 0, 0);
    s[3] = __builtin_amdgcn_mfma_f32_16x16x32_bf16(kf31, aq1, s[3], 0, 0, 0);
    __builtin_amdgcn_s_setprio(0);

    // shift-free softmax numerator: P = exp2(s) directly (bounded, no sub needed)
#pragma unroll
    for (int nj = 0; nj < 4; nj++) {
      float p0 = exp2f(s[nj][0]);
      float p1 = exp2f(s[nj][1]);
      float p2 = exp2f(s[nj][2]);
      float p3 = exp2f(s[nj][3]);
      // truncate-pack to bf16 pairs (scale-invariant rel err < 0.4%)
      u32 lo = (__float_as_uint(p1) & 0xffff0000u) | (__float_as_uint(p0) >> 16);
      u32 hi = (__float_as_uint(p3) & 0xffff0000u) | (__float_as_uint(p2) >> 16);
      u32x2 pr = {lo, hi};
      *(u32x2*)&Pls[(w * 16 + l15) * ASTR + nj * 16 + l16 * 4] = pr;
    }

    // O^T += V^T · P^T ; row-sum += ones · P^T (same B-frag, free normalizer)
    __builtin_amdgcn_s_setprio(1);
#pragma unroll
    for (int ks = 0; ks < 2; ks++) {
      short8 pb = *(const short8*)&Pls[(w * 16 + l15) * ASTR + ks * 32 + l16 * 8];
      osum = __builtin_amdgcn_mfma_f32_16x16x32_bf16(ones8, pb, osum, 0, 0, 0);
#pragma unroll
      for (int di = 0; di < 4; di++) {
        short8 vf = *(const short8*)&Vls[(di * 16 + l15) * ASTR + ks * 32 + l16 * 8];
        ot[di] = __builtin_amdgcn_mfma_f32_16x16x32_bf16(vf, pb, ot[di], 0, 0, 0);
      }
    }
    __builtin_amdgcn_s_setprio(0);
  }

  // osum[r] is the full P row-sum for q=l15 (replicated) — no reduce needed
  float inv = 1.f / osum[0];
  int token = b * 2048 + q0 + w * 16 + l15;
#pragma unroll
  for (int di = 0; di < 4; di++) {
    u16x4 pk4 = {f2bf(ot[di][0] * inv), f2bf(ot[di][1] * inv),
                 f2bf(ot[di][2] * inv), f2bf(ot[di][3] * inv)};
    *(u16x4*)&ab[(size_t)token * 384 + h * 64 + di * 16 + l16 * 4] = pk4;
  }
}

// ---------------- KNN (bf16 GH): u = G[idx] + (H[n]-G[n]+b); max over 8; leaky
// 8 bf16 per thread (one short8 gather per neighbor; idx loads halved)
__global__ void knn_kernel(const u16* __restrict__ GH, const int* __restrict__ kidx,
                           const float* __restrict__ kbias, u16* __restrict__ cat) {
  int f = blockIdx.x * 256 + threadIdx.x;
  if (f >= 16384 * 48) return;
  int token = f / 48, j8 = f - token * 48;
  int b = token >> 11, n = token & 2047;
  int j = j8 * 8;
  u16x8 gs = *(const u16x8*)&GH[(size_t)token * 768 + j];
  u16x8 hs = *(const u16x8*)&GH[(size_t)token * 768 + 384 + j];
  float d[8], m[8];
#pragma unroll
  for (int e = 0; e < 8; e++) {
    d[e] = b2f(hs[e]) - b2f(gs[e]) + kbias[j + e];
    m[e] = -1e30f;
  }
#pragma unroll
  for (int k = 0; k < 8; k++) {
    int t = kidx[(b * 8 + k) * 2048 + n];
    u16x8 g = *(const u16x8*)&GH[(size_t)t * 768 + j];
#pragma unroll
    for (int e = 0; e < 8; e++) m[e] = fmaxf(m[e], b2f(g[e]) + d[e]);
  }
  u16x8 pk;
#pragma unroll
  for (int e = 0; e < 8; e++) {
    float v = m[e] > 0.f ? m[e] : 0.2f * m[e];
    pk[e] = f2bf(v);
  }
  *(u16x8*)&cat[(size_t)token * 768 + 384 + j] = pk;
}

// ---------------- launch
extern "C" void kernel_launch(void* const* d_in, const int* in_sizes, int n_in,
                              void* d_out, int out_size, void* d_ws, size_t ws_size,
                              hipStream_t stream) {
  const float* x       = (const float*)d_in[0];
  const int*   kidx    = (const int*)d_in[1];
  const float* n1w     = (const float*)d_in[2];
  const float* n1b     = (const float*)d_in[3];
  const float* qkv_w   = (const float*)d_in[4];
  const float* proj_w  = (const float*)d_in[5];
  const float* proj_b  = (const float*)d_in[6];
  const float* knn_w   = (const float*)d_in[7];
  const float* knn_b   = (const float*)d_in[8];
  const float* merge_w = (const float*)d_in[9];
  const float* merge_b = (const float*)d_in[10];
  const float* n2w     = (const float*)d_in[11];
  const float* n2b     = (const float*)d_in[12];
  const float* fc1_w   = (const float*)d_in[13];
  const float* fc1_b   = (const float*)d_in[14];
  const float* fc2_w   = (const float*)d_in[15];
  const float* fc2_b   = (const float*)d_in[16];
  float* out = (float*)d_out;
  char* ws = (char*)d_ws;

  // ws layout (bytes)
  u16* wbig   = (u16*)(ws + 0);          // 1920x384 bf16: [qkv | knnW1 | knnW2]
  u16* wproj  = (u16*)(ws + 1474560);    // 384x384
  u16* wmerge = (u16*)(ws + 1769472);    // 384x768
  u16* wfc1   = (u16*)(ws + 2359296);    // 1536x384
  u16* wfc2   = (u16*)(ws + 3538944);    // 384x1536
  u16* nx     = (u16*)(ws + 4718592);    // norm_x bf16; later attn-out
  u16* qbf    = (u16*)(ws + 17301504);   // q (pre-scaled); later norm2 out
  u16* kbf    = (u16*)(ws + 29884416);   // k; later cat (spans k+vT)
  u16* vtb    = (u16*)(ws + 42467328);   // v transposed [b][h][d][n]
  u16* GH     = (u16*)(ws + 55050240);   // [16384][768] bf16; later h bf16
  float* xmid = (float*)(ws + 105381888);
  u16* cat = kbf;
  u16* n2  = qbf;
  u16* abf = nx;
  u16* hbf = GH;

  // merged weight transposes (7 jobs, 9216 blocks)
  TJobs J;
  J.in[0] = qkv_w;   J.outoff[0] = 0;       J.ld[0] = 1152; J.row0[0] = 0;   J.K[0] = 384;  J.blkend[0] = 1728;
  J.in[1] = knn_w;   J.outoff[1] = 884736;  J.ld[1] = 384;  J.row0[1] = 0;   J.K[1] = 384;  J.blkend[1] = 2304;
  J.in[2] = knn_w;   J.outoff[2] = 1179648; J.ld[2] = 384;  J.row0[2] = 384; J.K[2] = 384;  J.blkend[2] = 2880;
  J.in[3] = proj_w;  J.outoff[3] = 1474560; J.ld[3] = 384;  J.row0[3] = 0;   J.K[3] = 384;  J.blkend[3] = 3456;
  J.in[4] = merge_w; J.outoff[4] = 1769472; J.ld[4] = 384;  J.row0[4] = 0;   J.K[4] = 768;  J.blkend[4] = 4608;
  J.in[5] = fc1_w;   J.outoff[5] = 2359296; J.ld[5] = 1536; J.row0[5] = 0;   J.K[5] = 384;  J.blkend[5] = 6912;
  J.in[6] = fc2_w;   J.outoff[6] = 3538944; J.ld[6] = 384;  J.row0[6] = 0;   J.K[6] = 1536; J.blkend[6] = 9216;
  transpose_all_kernel<<<9216, 256, 0, stream>>>(J, ws);

  // LN1
  ln_kernel<<<16384, 64, 0, stream>>>(x, n1w, n1b, nx);
  // merged qkv+GH (split epilogue: q scaled, v transposed, GH bf16)
  gemm_kernel<2, 128><<<128 * 15, 256, 0, stream>>>(nx, wbig, 16384, 1920, 384, 0, nullptr, nullptr, qbf, kbf, vtb, GH);
  // attention -> abf (reuses nx space AFTER nx consumed); 8-wave blocks, grid 768
  attn_kernel<<<768, 512, 0, stream>>>(qbf, kbf, vtb, abf);
  // knn gather+max -> cat cols 384:768 (reuses k/v space AFTER attention)
  knn_kernel<<<3072, 256, 0, stream>>>(GH, kidx, knn_b, cat);
  // proj -> cat cols 0:384
  gemm_kernel<1, 64><<<128 * 6, 256, 0, stream>>>(abf, wproj, 16384, 384, 384, 768, proj_b, nullptr, cat, nullptr, nullptr, nullptr);
  // merge + residual -> xmid
  gemm_kernel<3, 64><<<128 * 6, 256, 0, stream>>>(cat, wmerge, 16384, 384, 768, 384, merge_b, x, xmid, nullptr, nullptr, nullptr);
  // LN2
  ln_kernel<<<16384, 64, 0, stream>>>(xmid, n2w, n2b, n2);
  // fc1 + gelu -> h (reuses GH space)
  gemm_kernel<4, 128><<<128 * 12, 256, 0, stream>>>(n2, wfc1, 16384, 1536, 384, 1536, fc1_b, nullptr, hbf, nullptr, nullptr, nullptr);
  // fc2 + residual -> out
  gemm_kernel<3, 64><<<128 * 6, 256, 0, stream>>>(hbf, wfc2, 16384, 384, 1536, 384, fc2_b, xmid, out, nullptr, nullptr, nullptr);
}

// Round 18
// 286.088 us; speedup vs baseline: 1.3450x; 1.3450x over previous
//
#include <hip/hip_runtime.h>

typedef unsigned short u16;
typedef unsigned int u32;
typedef __attribute__((ext_vector_type(8))) short short8;
typedef __attribute__((ext_vector_type(4))) u16 u16x4;
typedef __attribute__((ext_vector_type(8))) u16 u16x8;
typedef __attribute__((ext_vector_type(2))) u32 u32x2;
typedef __attribute__((ext_vector_type(4))) float f32x4;

__device__ __forceinline__ u16 f2bf(float f) {
  unsigned u = __float_as_uint(f);
  u += 0x7fffu + ((u >> 16) & 1u);
  return (u16)(u >> 16);
}
__device__ __forceinline__ float b2f(u16 v) { return __uint_as_float((u32)v << 16); }

// async global->LDS DMA, 16B per lane, linear dest (wave-uniform base + lane*16)
#define GLD16(g, l)                                                        \
  __builtin_amdgcn_global_load_lds(                                        \
      (const __attribute__((address_space(1))) void*)(g),                  \
      (__attribute__((address_space(3))) void*)(l), 16, 0, 0)

// ---------------- merged weight transpose+cast: 7 jobs in one launch
struct TJobs {
  const float* in[7];
  unsigned long long outoff[7];  // byte offset into ws
  int ld[7], row0[7], K[7], blkend[7];
};
__global__ void transpose_all_kernel(TJobs J, char* __restrict__ ws) {
  int bx = blockIdx.x;
  int ji = 0;
  while (bx >= J.blkend[ji]) ji++;
  int base = (ji == 0) ? 0 : J.blkend[ji - 1];
  int i = (bx - base) * 256 + threadIdx.x;
  int K = J.K[ji];
  int j = i / K, k = i - j * K;
  u16* out = (u16*)(ws + J.outoff[ji]);
  out[(size_t)j * K + k] = f2bf(J.in[ji][(size_t)(J.row0[ji] + k) * J.ld[ji] + j]);
}

// ---------------- LayerNorm: 1 wave per row of 384, 6 elems/lane
__global__ void ln_kernel(const float* __restrict__ in, const float* __restrict__ w,
                          const float* __restrict__ b, u16* __restrict__ out) {
  int row = blockIdx.x, t = threadIdx.x;
  const float* r = in + (size_t)row * 384;
  float v[6];
  float s = 0.f;
#pragma unroll
  for (int i = 0; i < 6; i++) { v[i] = r[t + 64 * i]; s += v[i]; }
#pragma unroll
  for (int off = 32; off > 0; off >>= 1) s += __shfl_xor(s, off);
  float mu = s * (1.f / 384.f);
  float q = 0.f;
#pragma unroll
  for (int i = 0; i < 6; i++) { float d = v[i] - mu; q += d * d; }
#pragma unroll
  for (int off = 32; off > 0; off >>= 1) q += __shfl_xor(q, off);
  float rstd = rsqrtf(q * (1.f / 384.f) + 1e-5f);
#pragma unroll
  for (int i = 0; i < 6; i++) {
    int j = t + 64 * i;
    out[(size_t)row * 384 + j] = f2bf((v[i] - mu) * rstd * w[j] + b[j]);
  }
}

// ---------------- bf16 MFMA GEMM: C[M,N] = A[M,K] * Bt[N,K]^T
// 128xTN tile, 256 thr (4 waves 2x2). BK=64 as two stacked [rows][32] half-tiles
// (m97's proven 64B-stride LDS layout; halves barrier drains per FLOP).
// MODE 1: bf16 out + bias (strided ldc)
// MODE 2: merged qkv+GH split: q(scaled)|k -> [t,384]; vT -> [b][h][d][n]; GH bf16 [t,768]
// MODE 3: f32 out = acc + bias + res   MODE 4: bf16 out = gelu(acc+bias), tanh-form
template <int MODE, int TN>
__global__ __launch_bounds__(256) void gemm_kernel(
    const u16* __restrict__ A, const u16* __restrict__ Bt,
    int M, int N, int K, int ldc,
    const float* __restrict__ bias, const float* __restrict__ res,
    void* __restrict__ out0, void* __restrict__ out1, void* __restrict__ out2,
    void* __restrict__ out3) {
  __shared__ u16 Als[2][128 * 32];
  __shared__ u16 Bls[2][TN * 32];
  const int NJ = TN / 32;  // N-frags per wave
  const int MB = M >> 7;
  int mb = blockIdx.x % MB, nb = blockIdx.x / MB;
  int m0 = mb << 7, n0 = nb * TN;
  int tid = threadIdx.x;
  int lane = tid & 63, w = tid >> 6;
  int wm = (w >> 1) << 6, wn = (w & 1) * (TN / 2);
  int l15 = lane & 15, l16 = lane >> 4;
  const f32x4 fz = {0.f, 0.f, 0.f, 0.f};
  f32x4 acc[4][NJ];
#pragma unroll
  for (int i = 0; i < 4; i++)
#pragma unroll
    for (int j = 0; j < NJ; j++) acc[i][j] = fz;

  // staging: lane l -> row +(l>>2), chunk (l&3)*8; one GLD16 covers 16 rows
  const int strow = lane >> 2, stch = (lane & 3) * 8;
  const u16* Ag = A + (size_t)(m0 + w * 32 + strow) * K + stch;
  const u16* Bg = Bt + (size_t)(n0 + w * (TN / 4) + strow) * K + stch;
  u16* Al0 = &Als[0][(w * 32) * 32];
  u16* Al1 = &Als[1][(w * 32) * 32];
  u16* Bl0 = &Bls[0][(w * (TN / 4)) * 32];
  u16* Bl1 = &Bls[1][(w * (TN / 4)) * 32];

  for (int k0 = 0; k0 < K; k0 += 64) {
    __syncthreads();  // prev tile's ds_reads done
    GLD16(Ag + k0, Al0);
    GLD16(Ag + k0 + (size_t)16 * K, Al0 + 16 * 32);
    GLD16(Ag + k0 + 32, Al1);
    GLD16(Ag + k0 + 32 + (size_t)16 * K, Al1 + 16 * 32);
    GLD16(Bg + k0, Bl0);
    GLD16(Bg + k0 + 32, Bl1);
    if (TN == 128) {
      GLD16(Bg + k0 + (size_t)16 * K, Bl0 + 16 * 32);
      GLD16(Bg + k0 + 32 + (size_t)16 * K, Bl1 + 16 * 32);
    }
    asm volatile("s_waitcnt vmcnt(0)" ::: "memory");  // drain LDS-DMA before barrier
    __syncthreads();
#pragma unroll
    for (int kk = 0; kk < 2; kk++) {
      short8 af[4], bfr[NJ];
#pragma unroll
      for (int i = 0; i < 4; i++)
        af[i] = *(const short8*)&Als[kk][(wm + i * 16 + l15) * 32 + l16 * 8];
#pragma unroll
      for (int j = 0; j < NJ; j++)
        bfr[j] = *(const short8*)&Bls[kk][(wn + j * 16 + l15) * 32 + l16 * 8];
      __builtin_amdgcn_s_setprio(1);
#pragma unroll
      for (int i = 0; i < 4; i++)
#pragma unroll
        for (int j = 0; j < NJ; j++)
          acc[i][j] = __builtin_amdgcn_mfma_f32_16x16x32_bf16(af[i], bfr[j], acc[i][j], 0, 0, 0);
      __builtin_amdgcn_s_setprio(0);
    }
  }

#pragma unroll
  for (int i = 0; i < 4; i++)
#pragma unroll
    for (int j = 0; j < NJ; j++)
#pragma unroll
      for (int r = 0; r < 4; r++) {
        int row = m0 + wm + i * 16 + l16 * 4 + r;
        int col = n0 + wn + j * 16 + l15;
        float v = acc[i][j][r];
        if (MODE == 1) {
          ((u16*)out0)[(size_t)row * ldc + col] = f2bf(v + bias[col]);
        } else if (MODE == 2) {
          if (col < 384) {
            ((u16*)out0)[(size_t)row * 384 + col] = f2bf(v * 0.18033688011112042f);
          } else if (col < 768) {
            ((u16*)out1)[(size_t)row * 384 + col - 384] = f2bf(v);
          } else if (col < 1152) {
            int df = col - 768, hh = df >> 6, dd = df & 63;
            ((u16*)out2)[(((size_t)(row >> 11) * 6 + hh) * 64 + dd) * 2048 + (row & 2047)] = f2bf(v);
          } else {
            ((u16*)out3)[(size_t)row * 768 + (col - 1152)] = f2bf(v);
          }
        } else if (MODE == 3) {
          ((float*)out0)[(size_t)row * ldc + col] = v + bias[col] + res[(size_t)row * ldc + col];
        } else if (MODE == 4) {
          float u = v + bias[col];
          // tanh-form GELU via exp2 (max dev from erf-GELU ~3e-4, threshold 0.115)
          float t = u * (0.79788456f + 0.03567741f * u * u);
          float g = u / (1.f + exp2f(-2.88539008f * t));
          ((u16*)out0)[(size_t)row * ldc + col] = f2bf(g);
        }
      }
}

// ---------------- flash attention (R14/R16 proven best): 8-wave blocks (128 q-rows)
// sharing K/V LDS, stride-80 rows. Swapped QK^T, shift-free softmax, row-sum via
// ones-MFMA. grid = B*H*(N/128) = 768 = 3 blocks/CU. R17's K-from-global A/B showed
// global K-frags are latency-bound (194us vs 90us) — LDS staging stays.
#define ASTR 80  // LDS row stride in u16 (160 B): 4-way max read conflicts, 16B-aligned
__global__ __launch_bounds__(512) void attn_kernel(const u16* __restrict__ qb,
                                                   const u16* __restrict__ kb,
                                                   const u16* __restrict__ vtb,
                                                   u16* __restrict__ ab) {
  __shared__ u16 Kls[64 * ASTR];
  __shared__ u16 Vls[64 * ASTR];    // [d][j] (V pre-transposed in global)
  __shared__ u16 Pls[128 * ASTR];   // Q staging (128 rows), then P[q][key] per-wave rows
  int bx = blockIdx.x;
  int q0 = (bx & 15) << 7;
  int h = (bx >> 4) % 6;
  int b = bx / 96;
  int tid = threadIdx.x, lane = tid & 63, w = tid >> 6;  // w in 0..7
  int l15 = lane & 15, l16 = lane >> 4;

  // stage Q (128 rows x 64 cols) into Pls; each wave then reads only its own 16 rows
  const size_t qbase = (size_t)(b * 2048 + q0) * 384 + h * 64;
  {
    int i0 = tid, i1 = 512 + tid;
    *(short8*)&Pls[(i0 >> 3) * ASTR + (i0 & 7) * 8] =
        *(const short8*)&qb[qbase + (size_t)(i0 >> 3) * 384 + (i0 & 7) * 8];
    *(short8*)&Pls[(i1 >> 3) * ASTR + (i1 & 7) * 8] =
        *(const short8*)&qb[qbase + (size_t)(i1 >> 3) * 384 + (i1 & 7) * 8];
  }
  __syncthreads();
  short8 aq0 = *(const short8*)&Pls[(w * 16 + l15) * ASTR + l16 * 8];
  short8 aq1 = *(const short8*)&Pls[(w * 16 + l15) * ASTR + 32 + l16 * 8];

  const f32x4 fz = {0.f, 0.f, 0.f, 0.f};
  f32x4 ot[4];   // O^T: lane q = l15; d = di*16 + l16*4 + r
  f32x4 osum;    // P row-sum via ones-MFMA; every element = full sum for q=l15
#pragma unroll
  for (int di = 0; di < 4; di++) ot[di] = fz;
  osum = fz;
  short8 ones8;  // constant all-ones bf16 A-fragment (1.0 = 0x3F80)
#pragma unroll
  for (int i = 0; i < 8; i++) ones8[i] = (short)0x3F80;

  const size_t kbase = (size_t)b * 2048 * 384 + h * 64;
  const size_t vbase = ((size_t)b * 6 + h) * 64 * 2048;
  // staging: 64 rows x 64 cols = 512 short8 slots; 512 threads -> 1 slot each
  const int srow = tid >> 3, sch = (tid & 7) * 8;

  // preload tile 0 into regs (T14-lite)
  short8 kr = *(const short8*)&kb[kbase + (size_t)srow * 384 + sch];
  short8 vr = *(const short8*)&vtb[vbase + (size_t)srow * 2048 + sch];

  for (int t = 0; t < 32; t++) {
    __syncthreads();  // previous tile's LDS reads done (and Q-staging consumed)
    *(short8*)&Kls[srow * ASTR + sch] = kr;
    *(short8*)&Vls[srow * ASTR + sch] = vr;
    if (t + 1 < 32) {  // issue next tile's loads; they fly during compute below
      int j0n = (t + 1) << 6;
      kr = *(const short8*)&kb[kbase + (size_t)(j0n + srow) * 384 + sch];
      vr = *(const short8*)&vtb[vbase + (size_t)srow * 2048 + j0n + sch];
    }
    __syncthreads();

    // S^T = K·Q^T : mfma(A=K_frag, B=Q_frag) -> col=q=l15, row=key
    f32x4 s[4];
    __builtin_amdgcn_s_setprio(1);
#pragma unroll
    for (int nj = 0; nj < 4; nj++) {
      short8 kf0 = *(const short8*)&Kls[(nj * 16 + l15) * ASTR + l16 * 8];
      short8 kf1 = *(const short8*)&Kls[(nj * 16 + l15) * ASTR + 32 + l16 * 8];
      s[nj] = __builtin_amdgcn_mfma_f32_16x16x32_bf16(kf0, aq0, fz, 0, 0, 0);
      s[nj] = __builtin_amdgcn_mfma_f32_16x16x32_bf16(kf1, aq1, s[nj], 0, 0, 0);
    }
    __builtin_amdgcn_s_setprio(0);

    // shift-free softmax numerator: P = exp2(s) directly (bounded, no sub needed)
#pragma unroll
    for (int nj = 0; nj < 4; nj++) {
      float p0 = exp2f(s[nj][0]);
      float p1 = exp2f(s[nj][1]);
      float p2 = exp2f(s[nj][2]);
      float p3 = exp2f(s[nj][3]);
      // truncate-pack to bf16 pairs (scale-invariant rel err < 0.4%)
      u32 lo = (__float_as_uint(p1) & 0xffff0000u) | (__float_as_uint(p0) >> 16);
      u32 hi = (__float_as_uint(p3) & 0xffff0000u) | (__float_as_uint(p2) >> 16);
      u32x2 pr = {lo, hi};
      *(u32x2*)&Pls[(w * 16 + l15) * ASTR + nj * 16 + l16 * 4] = pr;
    }

    // O^T += V^T · P^T ; row-sum += ones · P^T (same B-frag, free normalizer)
    __builtin_amdgcn_s_setprio(1);
#pragma unroll
    for (int ks = 0; ks < 2; ks++) {
      short8 pb = *(const short8*)&Pls[(w * 16 + l15) * ASTR + ks * 32 + l16 * 8];
      osum = __builtin_amdgcn_mfma_f32_16x16x32_bf16(ones8, pb, osum, 0, 0, 0);
#pragma unroll
      for (int di = 0; di < 4; di++) {
        short8 vf = *(const short8*)&Vls[(di * 16 + l15) * ASTR + ks * 32 + l16 * 8];
        ot[di] = __builtin_amdgcn_mfma_f32_16x16x32_bf16(vf, pb, ot[di], 0, 0, 0);
      }
    }
    __builtin_amdgcn_s_setprio(0);
  }

  // osum[r] is the full P row-sum for q=l15 (replicated) — no reduce needed
  float inv = 1.f / osum[0];
  int token = b * 2048 + q0 + w * 16 + l15;
#pragma unroll
  for (int di = 0; di < 4; di++) {
    u16x4 pk4 = {f2bf(ot[di][0] * inv), f2bf(ot[di][1] * inv),
                 f2bf(ot[di][2] * inv), f2bf(ot[di][3] * inv)};
    *(u16x4*)&ab[(size_t)token * 384 + h * 64 + di * 16 + l16 * 4] = pk4;
  }
}

// ---------------- KNN (bf16 GH): u = G[idx] + (H[n]-G[n]+b); max over 8; leaky
// 8 bf16 per thread (one short8 gather per neighbor; idx loads halved)
__global__ void knn_kernel(const u16* __restrict__ GH, const int* __restrict__ kidx,
                           const float* __restrict__ kbias, u16* __restrict__ cat) {
  int f = blockIdx.x * 256 + threadIdx.x;
  if (f >= 16384 * 48) return;
  int token = f / 48, j8 = f - token * 48;
  int b = token >> 11, n = token & 2047;
  int j = j8 * 8;
  u16x8 gs = *(const u16x8*)&GH[(size_t)token * 768 + j];
  u16x8 hs = *(const u16x8*)&GH[(size_t)token * 768 + 384 + j];
  float d[8], m[8];
#pragma unroll
  for (int e = 0; e < 8; e++) {
    d[e] = b2f(hs[e]) - b2f(gs[e]) + kbias[j + e];
    m[e] = -1e30f;
  }
#pragma unroll
  for (int k = 0; k < 8; k++) {
    int t = kidx[(b * 8 + k) * 2048 + n];
    u16x8 g = *(const u16x8*)&GH[(size_t)t * 768 + j];
#pragma unroll
    for (int e = 0; e < 8; e++) m[e] = fmaxf(m[e], b2f(g[e]) + d[e]);
  }
  u16x8 pk;
#pragma unroll
  for (int e = 0; e < 8; e++) {
    float v = m[e] > 0.f ? m[e] : 0.2f * m[e];
    pk[e] = f2bf(v);
  }
  *(u16x8*)&cat[(size_t)token * 768 + 384 + j] = pk;
}

// ---------------- launch
extern "C" void kernel_launch(void* const* d_in, const int* in_sizes, int n_in,
                              void* d_out, int out_size, void* d_ws, size_t ws_size,
                              hipStream_t stream) {
  const float* x       = (const float*)d_in[0];
  const int*   kidx    = (const int*)d_in[1];
  const float* n1w     = (const float*)d_in[2];
  const float* n1b     = (const float*)d_in[3];
  const float* qkv_w   = (const float*)d_in[4];
  const float* proj_w  = (const float*)d_in[5];
  const float* proj_b  = (const float*)d_in[6];
  const float* knn_w   = (const float*)d_in[7];
  const float* knn_b   = (const float*)d_in[8];
  const float* merge_w = (const float*)d_in[9];
  const float* merge_b = (const float*)d_in[10];
  const float* n2w     = (const float*)d_in[11];
  const float* n2b     = (const float*)d_in[12];
  const float* fc1_w   = (const float*)d_in[13];
  const float* fc1_b   = (const float*)d_in[14];
  const float* fc2_w   = (const float*)d_in[15];
  const float* fc2_b   = (const float*)d_in[16];
  float* out = (float*)d_out;
  char* ws = (char*)d_ws;

  // ws layout (bytes)
  u16* wbig   = (u16*)(ws + 0);          // 1920x384 bf16: [qkv | knnW1 | knnW2]
  u16* wproj  = (u16*)(ws + 1474560);    // 384x384
  u16* wmerge = (u16*)(ws + 1769472);    // 384x768
  u16* wfc1   = (u16*)(ws + 2359296);    // 1536x384
  u16* wfc2   = (u16*)(ws + 3538944);    // 384x1536
  u16* nx     = (u16*)(ws + 4718592);    // norm_x bf16; later attn-out
  u16* qbf    = (u16*)(ws + 17301504);   // q (pre-scaled); later norm2 out
  u16* kbf    = (u16*)(ws + 29884416);   // k; later cat (spans k+vT)
  u16* vtb    = (u16*)(ws + 42467328);   // v transposed [b][h][d][n]
  u16* GH     = (u16*)(ws + 55050240);   // [16384][768] bf16; later h bf16
  float* xmid = (float*)(ws + 105381888);
  u16* cat = kbf;
  u16* n2  = qbf;
  u16* abf = nx;
  u16* hbf = GH;

  // merged weight transposes (7 jobs, 9216 blocks)
  TJobs J;
  J.in[0] = qkv_w;   J.outoff[0] = 0;       J.ld[0] = 1152; J.row0[0] = 0;   J.K[0] = 384;  J.blkend[0] = 1728;
  J.in[1] = knn_w;   J.outoff[1] = 884736;  J.ld[1] = 384;  J.row0[1] = 0;   J.K[1] = 384;  J.blkend[1] = 2304;
  J.in[2] = knn_w;   J.outoff[2] = 1179648; J.ld[2] = 384;  J.row0[2] = 384; J.K[2] = 384;  J.blkend[2] = 2880;
  J.in[3] = proj_w;  J.outoff[3] = 1474560; J.ld[3] = 384;  J.row0[3] = 0;   J.K[3] = 384;  J.blkend[3] = 3456;
  J.in[4] = merge_w; J.outoff[4] = 1769472; J.ld[4] = 384;  J.row0[4] = 0;   J.K[4] = 768;  J.blkend[4] = 4608;
  J.in[5] = fc1_w;   J.outoff[5] = 2359296; J.ld[5] = 1536; J.row0[5] = 0;   J.K[5] = 384;  J.blkend[5] = 6912;
  J.in[6] = fc2_w;   J.outoff[6] = 3538944; J.ld[6] = 384;  J.row0[6] = 0;   J.K[6] = 1536; J.blkend[6] = 9216;
  transpose_all_kernel<<<9216, 256, 0, stream>>>(J, ws);

  // LN1
  ln_kernel<<<16384, 64, 0, stream>>>(x, n1w, n1b, nx);
  // merged qkv+GH (split epilogue: q scaled, v transposed, GH bf16)
  gemm_kernel<2, 128><<<128 * 15, 256, 0, stream>>>(nx, wbig, 16384, 1920, 384, 0, nullptr, nullptr, qbf, kbf, vtb, GH);
  // attention -> abf (reuses nx space AFTER nx consumed); 8-wave blocks, grid 768
  attn_kernel<<<768, 512, 0, stream>>>(qbf, kbf, vtb, abf);
  // knn gather+max -> cat cols 384:768 (reuses k/v space AFTER attention)
  knn_kernel<<<3072, 256, 0, stream>>>(GH, kidx, knn_b, cat);
  // proj -> cat cols 0:384
  gemm_kernel<1, 64><<<128 * 6, 256, 0, stream>>>(abf, wproj, 16384, 384, 384, 768, proj_b, nullptr, cat, nullptr, nullptr, nullptr);
  // merge + residual -> xmid
  gemm_kernel<3, 64><<<128 * 6, 256, 0, stream>>>(cat, wmerge, 16384, 384, 768, 384, merge_b, x, xmid, nullptr, nullptr, nullptr);
  // LN2
  ln_kernel<<<16384, 64, 0, stream>>>(xmid, n2w, n2b, n2);
  // fc1 + gelu -> h (reuses GH space)
  gemm_kernel<4, 128><<<128 * 12, 256, 0, stream>>>(n2, wfc1, 16384, 1536, 384, 1536, fc1_b, nullptr, hbf, nullptr, nullptr, nullptr);
  // fc2 + residual -> out
  gemm_kernel<3, 64><<<128 * 6, 256, 0, stream>>>(hbf, wfc2, 16384, 384, 1536, 384, fc2_b, xmid, out, nullptr, nullptr, nullptr);
}

// Round 19
// 279.692 us; speedup vs baseline: 1.3757x; 1.0229x over previous
//
#include <hip/hip_runtime.h>

typedef unsigned short u16;
typedef unsigned int u32;
typedef __attribute__((ext_vector_type(8))) short short8;
typedef __attribute__((ext_vector_type(4))) u16 u16x4;
typedef __attribute__((ext_vector_type(8))) u16 u16x8;
typedef __attribute__((ext_vector_type(2))) u32 u32x2;
typedef __attribute__((ext_vector_type(4))) float f32x4;

__device__ __forceinline__ u16 f2bf(float f) {
  unsigned u = __float_as_uint(f);
  u += 0x7fffu + ((u >> 16) & 1u);
  return (u16)(u >> 16);
}
__device__ __forceinline__ float b2f(u16 v) { return __uint_as_float((u32)v << 16); }

// async global->LDS DMA, 16B per lane, linear dest (wave-uniform base + lane*16)
#define GLD16(g, l)                                                        \
  __builtin_amdgcn_global_load_lds(                                        \
      (const __attribute__((address_space(1))) void*)(g),                  \
      (__attribute__((address_space(3))) void*)(l), 16, 0, 0)

// ---------------- merged weight transpose+cast: 7 jobs in one launch
struct TJobs {
  const float* in[7];
  unsigned long long outoff[7];  // byte offset into ws
  int ld[7], row0[7], K[7], blkend[7];
};
__global__ void transpose_all_kernel(TJobs J, char* __restrict__ ws) {
  int bx = blockIdx.x;
  int ji = 0;
  while (bx >= J.blkend[ji]) ji++;
  int base = (ji == 0) ? 0 : J.blkend[ji - 1];
  int i = (bx - base) * 256 + threadIdx.x;
  int K = J.K[ji];
  int j = i / K, k = i - j * K;
  u16* out = (u16*)(ws + J.outoff[ji]);
  out[(size_t)j * K + k] = f2bf(J.in[ji][(size_t)(J.row0[ji] + k) * J.ld[ji] + j]);
}

// ---------------- LayerNorm (f32 in): 1 wave per row of 384, 6 elems/lane
__global__ void ln_kernel(const float* __restrict__ in, const float* __restrict__ w,
                          const float* __restrict__ b, u16* __restrict__ out) {
  int row = blockIdx.x, t = threadIdx.x;
  const float* r = in + (size_t)row * 384;
  float v[6];
  float s = 0.f;
#pragma unroll
  for (int i = 0; i < 6; i++) { v[i] = r[t + 64 * i]; s += v[i]; }
#pragma unroll
  for (int off = 32; off > 0; off >>= 1) s += __shfl_xor(s, off);
  float mu = s * (1.f / 384.f);
  float q = 0.f;
#pragma unroll
  for (int i = 0; i < 6; i++) { float d = v[i] - mu; q += d * d; }
#pragma unroll
  for (int off = 32; off > 0; off >>= 1) q += __shfl_xor(q, off);
  float rstd = rsqrtf(q * (1.f / 384.f) + 1e-5f);
#pragma unroll
  for (int i = 0; i < 6; i++) {
    int j = t + 64 * i;
    out[(size_t)row * 384 + j] = f2bf((v[i] - mu) * rstd * w[j] + b[j]);
  }
}

// ---------------- LayerNorm (bf16 in): same structure, half the read traffic
__global__ void ln_bf16_kernel(const u16* __restrict__ in, const float* __restrict__ w,
                               const float* __restrict__ b, u16* __restrict__ out) {
  int row = blockIdx.x, t = threadIdx.x;
  const u16* r = in + (size_t)row * 384;
  float v[6];
  float s = 0.f;
#pragma unroll
  for (int i = 0; i < 6; i++) { v[i] = b2f(r[t + 64 * i]); s += v[i]; }
#pragma unroll
  for (int off = 32; off > 0; off >>= 1) s += __shfl_xor(s, off);
  float mu = s * (1.f / 384.f);
  float q = 0.f;
#pragma unroll
  for (int i = 0; i < 6; i++) { float d = v[i] - mu; q += d * d; }
#pragma unroll
  for (int off = 32; off > 0; off >>= 1) q += __shfl_xor(q, off);
  float rstd = rsqrtf(q * (1.f / 384.f) + 1e-5f);
#pragma unroll
  for (int i = 0; i < 6; i++) {
    int j = t + 64 * i;
    out[(size_t)row * 384 + j] = f2bf((v[i] - mu) * rstd * w[j] + b[j]);
  }
}

// ---------------- bf16 MFMA GEMM: C[M,N] = A[M,K] * Bt[N,K]^T
// 128xTN tile, 256 thr (4 waves 2x2). BK=64 as two stacked [rows][32] half-tiles.
// MODE 1: bf16 out + bias   MODE 2: merged qkv+GH split epilogue
// MODE 4: bf16 out = gelu(acc+bias), tanh-form
// MODE 5: bf16 out = acc + bias + res_f32   MODE 6: f32 out = acc + bias + res_bf16
template <int MODE, int TN>
__global__ __launch_bounds__(256) void gemm_kernel(
    const u16* __restrict__ A, const u16* __restrict__ Bt,
    int M, int N, int K, int ldc,
    const float* __restrict__ bias, const void* __restrict__ res,
    void* __restrict__ out0, void* __restrict__ out1, void* __restrict__ out2,
    void* __restrict__ out3) {
  __shared__ u16 Als[2][128 * 32];
  __shared__ u16 Bls[2][TN * 32];
  const int NJ = TN / 32;  // N-frags per wave
  const int MB = M >> 7;
  int mb = blockIdx.x % MB, nb = blockIdx.x / MB;
  int m0 = mb << 7, n0 = nb * TN;
  int tid = threadIdx.x;
  int lane = tid & 63, w = tid >> 6;
  int wm = (w >> 1) << 6, wn = (w & 1) * (TN / 2);
  int l15 = lane & 15, l16 = lane >> 4;
  const f32x4 fz = {0.f, 0.f, 0.f, 0.f};
  f32x4 acc[4][NJ];
#pragma unroll
  for (int i = 0; i < 4; i++)
#pragma unroll
    for (int j = 0; j < NJ; j++) acc[i][j] = fz;

  // staging: lane l -> row +(l>>2), chunk (l&3)*8; one GLD16 covers 16 rows
  const int strow = lane >> 2, stch = (lane & 3) * 8;
  const u16* Ag = A + (size_t)(m0 + w * 32 + strow) * K + stch;
  const u16* Bg = Bt + (size_t)(n0 + w * (TN / 4) + strow) * K + stch;
  u16* Al0 = &Als[0][(w * 32) * 32];
  u16* Al1 = &Als[1][(w * 32) * 32];
  u16* Bl0 = &Bls[0][(w * (TN / 4)) * 32];
  u16* Bl1 = &Bls[1][(w * (TN / 4)) * 32];

  for (int k0 = 0; k0 < K; k0 += 64) {
    __syncthreads();  // prev tile's ds_reads done
    GLD16(Ag + k0, Al0);
    GLD16(Ag + k0 + (size_t)16 * K, Al0 + 16 * 32);
    GLD16(Ag + k0 + 32, Al1);
    GLD16(Ag + k0 + 32 + (size_t)16 * K, Al1 + 16 * 32);
    GLD16(Bg + k0, Bl0);
    GLD16(Bg + k0 + 32, Bl1);
    if (TN == 128) {
      GLD16(Bg + k0 + (size_t)16 * K, Bl0 + 16 * 32);
      GLD16(Bg + k0 + 32 + (size_t)16 * K, Bl1 + 16 * 32);
    }
    asm volatile("s_waitcnt vmcnt(0)" ::: "memory");  // drain LDS-DMA before barrier
    __syncthreads();
#pragma unroll
    for (int kk = 0; kk < 2; kk++) {
      short8 af[4], bfr[NJ];
#pragma unroll
      for (int i = 0; i < 4; i++)
        af[i] = *(const short8*)&Als[kk][(wm + i * 16 + l15) * 32 + l16 * 8];
#pragma unroll
      for (int j = 0; j < NJ; j++)
        bfr[j] = *(const short8*)&Bls[kk][(wn + j * 16 + l15) * 32 + l16 * 8];
      __builtin_amdgcn_s_setprio(1);
#pragma unroll
      for (int i = 0; i < 4; i++)
#pragma unroll
        for (int j = 0; j < NJ; j++)
          acc[i][j] = __builtin_amdgcn_mfma_f32_16x16x32_bf16(af[i], bfr[j], acc[i][j], 0, 0, 0);
      __builtin_amdgcn_s_setprio(0);
    }
  }

#pragma unroll
  for (int i = 0; i < 4; i++)
#pragma unroll
    for (int j = 0; j < NJ; j++)
#pragma unroll
      for (int r = 0; r < 4; r++) {
        int row = m0 + wm + i * 16 + l16 * 4 + r;
        int col = n0 + wn + j * 16 + l15;
        float v = acc[i][j][r];
        if (MODE == 1) {
          ((u16*)out0)[(size_t)row * ldc + col] = f2bf(v + bias[col]);
        } else if (MODE == 2) {
          if (col < 384) {
            ((u16*)out0)[(size_t)row * 384 + col] = f2bf(v * 0.18033688011112042f);
          } else if (col < 768) {
            ((u16*)out1)[(size_t)row * 384 + col - 384] = f2bf(v);
          } else if (col < 1152) {
            int df = col - 768, hh = df >> 6, dd = df & 63;
            ((u16*)out2)[(((size_t)(row >> 11) * 6 + hh) * 64 + dd) * 2048 + (row & 2047)] = f2bf(v);
          } else {
            ((u16*)out3)[(size_t)row * 768 + (col - 1152)] = f2bf(v);
          }
        } else if (MODE == 4) {
          float u = v + bias[col];
          // tanh-form GELU via exp2 (max dev from erf-GELU ~3e-4, threshold 0.115)
          float t = u * (0.79788456f + 0.03567741f * u * u);
          float g = u / (1.f + exp2f(-2.88539008f * t));
          ((u16*)out0)[(size_t)row * ldc + col] = f2bf(g);
        } else if (MODE == 5) {
          float rv = ((const float*)res)[(size_t)row * ldc + col];
          ((u16*)out0)[(size_t)row * ldc + col] = f2bf(v + bias[col] + rv);
        } else if (MODE == 6) {
          float rv = b2f(((const u16*)res)[(size_t)row * ldc + col]);
          ((float*)out0)[(size_t)row * ldc + col] = v + bias[col] + rv;
        }
      }
}

// ---------------- flash attention (R14/R16 proven best): 8-wave blocks (128 q-rows)
// sharing K/V LDS, stride-80 rows. Swapped QK^T, shift-free softmax, row-sum via
// ones-MFMA. grid = B*H*(N/128) = 768 = 3 blocks/CU.
#define ASTR 80  // LDS row stride in u16 (160 B): 4-way max read conflicts, 16B-aligned
__global__ __launch_bounds__(512) void attn_kernel(const u16* __restrict__ qb,
                                                   const u16* __restrict__ kb,
                                                   const u16* __restrict__ vtb,
                                                   u16* __restrict__ ab) {
  __shared__ u16 Kls[64 * ASTR];
  __shared__ u16 Vls[64 * ASTR];    // [d][j] (V pre-transposed in global)
  __shared__ u16 Pls[128 * ASTR];   // Q staging (128 rows), then P[q][key] per-wave rows
  int bx = blockIdx.x;
  int q0 = (bx & 15) << 7;
  int h = (bx >> 4) % 6;
  int b = bx / 96;
  int tid = threadIdx.x, lane = tid & 63, w = tid >> 6;  // w in 0..7
  int l15 = lane & 15, l16 = lane >> 4;

  // stage Q (128 rows x 64 cols) into Pls; each wave then reads only its own 16 rows
  const size_t qbase = (size_t)(b * 2048 + q0) * 384 + h * 64;
  {
    int i0 = tid, i1 = 512 + tid;
    *(short8*)&Pls[(i0 >> 3) * ASTR + (i0 & 7) * 8] =
        *(const short8*)&qb[qbase + (size_t)(i0 >> 3) * 384 + (i0 & 7) * 8];
    *(short8*)&Pls[(i1 >> 3) * ASTR + (i1 & 7) * 8] =
        *(const short8*)&qb[qbase + (size_t)(i1 >> 3) * 384 + (i1 & 7) * 8];
  }
  __syncthreads();
  short8 aq0 = *(const short8*)&Pls[(w * 16 + l15) * ASTR + l16 * 8];
  short8 aq1 = *(const short8*)&Pls[(w * 16 + l15) * ASTR + 32 + l16 * 8];

  const f32x4 fz = {0.f, 0.f, 0.f, 0.f};
  f32x4 ot[4];   // O^T: lane q = l15; d = di*16 + l16*4 + r
  f32x4 osum;    // P row-sum via ones-MFMA; every element = full sum for q=l15
#pragma unroll
  for (int di = 0; di < 4; di++) ot[di] = fz;
  osum = fz;
  short8 ones8;  // constant all-ones bf16 A-fragment (1.0 = 0x3F80)
#pragma unroll
  for (int i = 0; i < 8; i++) ones8[i] = (short)0x3F80;

  const size_t kbase = (size_t)b * 2048 * 384 + h * 64;
  const size_t vbase = ((size_t)b * 6 + h) * 64 * 2048;
  // staging: 64 rows x 64 cols = 512 short8 slots; 512 threads -> 1 slot each
  const int srow = tid >> 3, sch = (tid & 7) * 8;

  // preload tile 0 into regs (T14-lite)
  short8 kr = *(const short8*)&kb[kbase + (size_t)srow * 384 + sch];
  short8 vr = *(const short8*)&vtb[vbase + (size_t)srow * 2048 + sch];

  for (int t = 0; t < 32; t++) {
    __syncthreads();  // previous tile's LDS reads done (and Q-staging consumed)
    *(short8*)&Kls[srow * ASTR + sch] = kr;
    *(short8*)&Vls[srow * ASTR + sch] = vr;
    if (t + 1 < 32) {  // issue next tile's loads; they fly during compute below
      int j0n = (t + 1) << 6;
      kr = *(const short8*)&kb[kbase + (size_t)(j0n + srow) * 384 + sch];
      vr = *(const short8*)&vtb[vbase + (size_t)srow * 2048 + j0n + sch];
    }
    __syncthreads();

    // S^T = K·Q^T : mfma(A=K_frag, B=Q_frag) -> col=q=l15, row=key
    f32x4 s[4];
    __builtin_amdgcn_s_setprio(1);
#pragma unroll
    for (int nj = 0; nj < 4; nj++) {
      short8 kf0 = *(const short8*)&Kls[(nj * 16 + l15) * ASTR + l16 * 8];
      short8 kf1 = *(const short8*)&Kls[(nj * 16 + l15) * ASTR + 32 + l16 * 8];
      s[nj] = __builtin_amdgcn_mfma_f32_16x16x32_bf16(kf0, aq0, fz, 0, 0, 0);
      s[nj] = __builtin_amdgcn_mfma_f32_16x16x32_bf16(kf1, aq1, s[nj], 0, 0, 0);
    }
    __builtin_amdgcn_s_setprio(0);

    // shift-free softmax numerator: P = exp2(s) directly (bounded, no sub needed)
#pragma unroll
    for (int nj = 0; nj < 4; nj++) {
      float p0 = exp2f(s[nj][0]);
      float p1 = exp2f(s[nj][1]);
      float p2 = exp2f(s[nj][2]);
      float p3 = exp2f(s[nj][3]);
      // truncate-pack to bf16 pairs (scale-invariant rel err < 0.4%)
      u32 lo = (__float_as_uint(p1) & 0xffff0000u) | (__float_as_uint(p0) >> 16);
      u32 hi = (__float_as_uint(p3) & 0xffff0000u) | (__float_as_uint(p2) >> 16);
      u32x2 pr = {lo, hi};
      *(u32x2*)&Pls[(w * 16 + l15) * ASTR + nj * 16 + l16 * 4] = pr;
    }

    // O^T += V^T · P^T ; row-sum += ones · P^T (same B-frag, free normalizer)
    __builtin_amdgcn_s_setprio(1);
#pragma unroll
    for (int ks = 0; ks < 2; ks++) {
      short8 pb = *(const short8*)&Pls[(w * 16 + l15) * ASTR + ks * 32 + l16 * 8];
      osum = __builtin_amdgcn_mfma_f32_16x16x32_bf16(ones8, pb, osum, 0, 0, 0);
#pragma unroll
      for (int di = 0; di < 4; di++) {
        short8 vf = *(const short8*)&Vls[(di * 16 + l15) * ASTR + ks * 32 + l16 * 8];
        ot[di] = __builtin_amdgcn_mfma_f32_16x16x32_bf16(vf, pb, ot[di], 0, 0, 0);
      }
    }
    __builtin_amdgcn_s_setprio(0);
  }

  // osum[r] is the full P row-sum for q=l15 (replicated) — no reduce needed
  float inv = 1.f / osum[0];
  int token = b * 2048 + q0 + w * 16 + l15;
#pragma unroll
  for (int di = 0; di < 4; di++) {
    u16x4 pk4 = {f2bf(ot[di][0] * inv), f2bf(ot[di][1] * inv),
                 f2bf(ot[di][2] * inv), f2bf(ot[di][3] * inv)};
    *(u16x4*)&ab[(size_t)token * 384 + h * 64 + di * 16 + l16 * 4] = pk4;
  }
}

// ---------------- KNN (bf16 GH): u = G[idx] + (H[n]-G[n]+b); max over 8; leaky
// 8 bf16 per thread (one short8 gather per neighbor; idx loads halved)
__global__ void knn_kernel(const u16* __restrict__ GH, const int* __restrict__ kidx,
                           const float* __restrict__ kbias, u16* __restrict__ cat) {
  int f = blockIdx.x * 256 + threadIdx.x;
  if (f >= 16384 * 48) return;
  int token = f / 48, j8 = f - token * 48;
  int b = token >> 11, n = token & 2047;
  int j = j8 * 8;
  u16x8 gs = *(const u16x8*)&GH[(size_t)token * 768 + j];
  u16x8 hs = *(const u16x8*)&GH[(size_t)token * 768 + 384 + j];
  float d[8], m[8];
#pragma unroll
  for (int e = 0; e < 8; e++) {
    d[e] = b2f(hs[e]) - b2f(gs[e]) + kbias[j + e];
    m[e] = -1e30f;
  }
#pragma unroll
  for (int k = 0; k < 8; k++) {
    int t = kidx[(b * 8 + k) * 2048 + n];
    u16x8 g = *(const u16x8*)&GH[(size_t)t * 768 + j];
#pragma unroll
    for (int e = 0; e < 8; e++) m[e] = fmaxf(m[e], b2f(g[e]) + d[e]);
  }
  u16x8 pk;
#pragma unroll
  for (int e = 0; e < 8; e++) {
    float v = m[e] > 0.f ? m[e] : 0.2f * m[e];
    pk[e] = f2bf(v);
  }
  *(u16x8*)&cat[(size_t)token * 768 + 384 + j] = pk;
}

// ---------------- launch
extern "C" void kernel_launch(void* const* d_in, const int* in_sizes, int n_in,
                              void* d_out, int out_size, void* d_ws, size_t ws_size,
                              hipStream_t stream) {
  const float* x       = (const float*)d_in[0];
  const int*   kidx    = (const int*)d_in[1];
  const float* n1w     = (const float*)d_in[2];
  const float* n1b     = (const float*)d_in[3];
  const float* qkv_w   = (const float*)d_in[4];
  const float* proj_w  = (const float*)d_in[5];
  const float* proj_b  = (const float*)d_in[6];
  const float* knn_w   = (const float*)d_in[7];
  const float* knn_b   = (const float*)d_in[8];
  const float* merge_w = (const float*)d_in[9];
  const float* merge_b = (const float*)d_in[10];
  const float* n2w     = (const float*)d_in[11];
  const float* n2b     = (const float*)d_in[12];
  const float* fc1_w   = (const float*)d_in[13];
  const float* fc1_b   = (const float*)d_in[14];
  const float* fc2_w   = (const float*)d_in[15];
  const float* fc2_b   = (const float*)d_in[16];
  float* out = (float*)d_out;
  char* ws = (char*)d_ws;

  // ws layout (bytes)
  u16* wbig   = (u16*)(ws + 0);          // 1920x384 bf16: [qkv | knnW1 | knnW2]
  u16* wproj  = (u16*)(ws + 1474560);    // 384x384
  u16* wmerge = (u16*)(ws + 1769472);    // 384x768
  u16* wfc1   = (u16*)(ws + 2359296);    // 1536x384
  u16* wfc2   = (u16*)(ws + 3538944);    // 384x1536
  u16* nx     = (u16*)(ws + 4718592);    // norm_x bf16; later attn-out
  u16* qbf    = (u16*)(ws + 17301504);   // q (pre-scaled); later norm2 out
  u16* kbf    = (u16*)(ws + 29884416);   // k; later cat (spans k+vT)
  u16* vtb    = (u16*)(ws + 42467328);   // v transposed [b][h][d][n]
  u16* GH     = (u16*)(ws + 55050240);   // [16384][768] bf16; later h bf16
  u16* xmid   = (u16*)(ws + 105381888);  // [16384][384] bf16 (was f32)
  u16* cat = kbf;
  u16* n2  = qbf;
  u16* abf = nx;
  u16* hbf = GH;

  // merged weight transposes (7 jobs, 9216 blocks)
  TJobs J;
  J.in[0] = qkv_w;   J.outoff[0] = 0;       J.ld[0] = 1152; J.row0[0] = 0;   J.K[0] = 384;  J.blkend[0] = 1728;
  J.in[1] = knn_w;   J.outoff[1] = 884736;  J.ld[1] = 384;  J.row0[1] = 0;   J.K[1] = 384;  J.blkend[1] = 2304;
  J.in[2] = knn_w;   J.outoff[2] = 1179648; J.ld[2] = 384;  J.row0[2] = 384; J.K[2] = 384;  J.blkend[2] = 2880;
  J.in[3] = proj_w;  J.outoff[3] = 1474560; J.ld[3] = 384;  J.row0[3] = 0;   J.K[3] = 384;  J.blkend[3] = 3456;
  J.in[4] = merge_w; J.outoff[4] = 1769472; J.ld[4] = 384;  J.row0[4] = 0;   J.K[4] = 768;  J.blkend[4] = 4608;
  J.in[5] = fc1_w;   J.outoff[5] = 2359296; J.ld[5] = 1536; J.row0[5] = 0;   J.K[5] = 384;  J.blkend[5] = 6912;
  J.in[6] = fc2_w;   J.outoff[6] = 3538944; J.ld[6] = 384;  J.row0[6] = 0;   J.K[6] = 1536; J.blkend[6] = 9216;
  transpose_all_kernel<<<9216, 256, 0, stream>>>(J, ws);

  // LN1
  ln_kernel<<<16384, 64, 0, stream>>>(x, n1w, n1b, nx);
  // merged qkv+GH (split epilogue: q scaled, v transposed, GH bf16)
  gemm_kernel<2, 128><<<128 * 15, 256, 0, stream>>>(nx, wbig, 16384, 1920, 384, 0, nullptr, nullptr, qbf, kbf, vtb, GH);
  // attention -> abf (reuses nx space AFTER nx consumed); 8-wave blocks, grid 768
  attn_kernel<<<768, 512, 0, stream>>>(qbf, kbf, vtb, abf);
  // knn gather+max -> cat cols 384:768 (reuses k/v space AFTER attention)
  knn_kernel<<<3072, 256, 0, stream>>>(GH, kidx, knn_b, cat);
  // proj -> cat cols 0:384
  gemm_kernel<1, 64><<<128 * 6, 256, 0, stream>>>(abf, wproj, 16384, 384, 384, 768, proj_b, nullptr, cat, nullptr, nullptr, nullptr);
  // merge + f32 residual -> xmid (bf16)
  gemm_kernel<5, 64><<<128 * 6, 256, 0, stream>>>(cat, wmerge, 16384, 384, 768, 384, merge_b, x, xmid, nullptr, nullptr, nullptr);
  // LN2 (bf16 in)
  ln_bf16_kernel<<<16384, 64, 0, stream>>>(xmid, n2w, n2b, n2);
  // fc1 + gelu -> h (TN=64: 3072 blocks, 6 resident/CU, no occupancy tail)
  gemm_kernel<4, 64><<<128 * 24, 256, 0, stream>>>(n2, wfc1, 16384, 1536, 384, 1536, fc1_b, nullptr, hbf, nullptr, nullptr, nullptr);
  // fc2 + bf16 residual -> out (f32)
  gemm_kernel<6, 64><<<128 * 6, 256, 0, stream>>>(hbf, wfc2, 16384, 384, 1536, 384, fc2_b, xmid, out, nullptr, nullptr, nullptr);
}

// Round 20
// 279.573 us; speedup vs baseline: 1.3763x; 1.0004x over previous
//
#include <hip/hip_runtime.h>

typedef unsigned short u16;
typedef unsigned int u32;
typedef __attribute__((ext_vector_type(8))) short short8;
typedef __attribute__((ext_vector_type(4))) u16 u16x4;
typedef __attribute__((ext_vector_type(8))) u16 u16x8;
typedef __attribute__((ext_vector_type(2))) u32 u32x2;
typedef __attribute__((ext_vector_type(4))) float f32x4;

__device__ __forceinline__ u16 f2bf(float f) {
  unsigned u = __float_as_uint(f);
  u += 0x7fffu + ((u >> 16) & 1u);
  return (u16)(u >> 16);
}
__device__ __forceinline__ float b2f(u16 v) { return __uint_as_float((u32)v << 16); }

// async global->LDS DMA, 16B per lane, linear dest (wave-uniform base + lane*16)
#define GLD16(g, l)                                                        \
  __builtin_amdgcn_global_load_lds(                                        \
      (const __attribute__((address_space(1))) void*)(g),                  \
      (__attribute__((address_space(3))) void*)(l), 16, 0, 0)

// ---------------- merged weight transpose+cast: 7 jobs in one launch
struct TJobs {
  const float* in[7];
  unsigned long long outoff[7];  // byte offset into ws
  int ld[7], row0[7], K[7], blkend[7];
};
__global__ void transpose_all_kernel(TJobs J, char* __restrict__ ws) {
  int bx = blockIdx.x;
  int ji = 0;
  while (bx >= J.blkend[ji]) ji++;
  int base = (ji == 0) ? 0 : J.blkend[ji - 1];
  int i = (bx - base) * 256 + threadIdx.x;
  int K = J.K[ji];
  int j = i / K, k = i - j * K;
  u16* out = (u16*)(ws + J.outoff[ji]);
  out[(size_t)j * K + k] = f2bf(J.in[ji][(size_t)(J.row0[ji] + k) * J.ld[ji] + j]);
}

// ---------------- LayerNorm (f32 in): 1 wave per row of 384, 6 elems/lane
__global__ void ln_kernel(const float* __restrict__ in, const float* __restrict__ w,
                          const float* __restrict__ b, u16* __restrict__ out) {
  int row = blockIdx.x, t = threadIdx.x;
  const float* r = in + (size_t)row * 384;
  float v[6];
  float s = 0.f;
#pragma unroll
  for (int i = 0; i < 6; i++) { v[i] = r[t + 64 * i]; s += v[i]; }
#pragma unroll
  for (int off = 32; off > 0; off >>= 1) s += __shfl_xor(s, off);
  float mu = s * (1.f / 384.f);
  float q = 0.f;
#pragma unroll
  for (int i = 0; i < 6; i++) { float d = v[i] - mu; q += d * d; }
#pragma unroll
  for (int off = 32; off > 0; off >>= 1) q += __shfl_xor(q, off);
  float rstd = rsqrtf(q * (1.f / 384.f) + 1e-5f);
#pragma unroll
  for (int i = 0; i < 6; i++) {
    int j = t + 64 * i;
    out[(size_t)row * 384 + j] = f2bf((v[i] - mu) * rstd * w[j] + b[j]);
  }
}

// ---------------- LayerNorm (bf16 in): same structure, half the read traffic
__global__ void ln_bf16_kernel(const u16* __restrict__ in, const float* __restrict__ w,
                               const float* __restrict__ b, u16* __restrict__ out) {
  int row = blockIdx.x, t = threadIdx.x;
  const u16* r = in + (size_t)row * 384;
  float v[6];
  float s = 0.f;
#pragma unroll
  for (int i = 0; i < 6; i++) { v[i] = b2f(r[t + 64 * i]); s += v[i]; }
#pragma unroll
  for (int off = 32; off > 0; off >>= 1) s += __shfl_xor(s, off);
  float mu = s * (1.f / 384.f);
  float q = 0.f;
#pragma unroll
  for (int i = 0; i < 6; i++) { float d = v[i] - mu; q += d * d; }
#pragma unroll
  for (int off = 32; off > 0; off >>= 1) q += __shfl_xor(q, off);
  float rstd = rsqrtf(q * (1.f / 384.f) + 1e-5f);
#pragma unroll
  for (int i = 0; i < 6; i++) {
    int j = t + 64 * i;
    out[(size_t)row * 384 + j] = f2bf((v[i] - mu) * rstd * w[j] + b[j]);
  }
}

// ---------------- bf16 MFMA GEMM: C[M,N] = A[M,K] * Bt[N,K]^T
// 128xTN tile, 256 thr (4 waves 2x2). BK=64 as two stacked [rows][32] half-tiles.
// MODE 1: bf16 out + bias   MODE 2: merged qkv+GH split epilogue
// MODE 4: bf16 out = gelu(acc+bias), tanh-form
// MODE 5: bf16 out = acc + bias + res_f32   MODE 6: f32 out = acc + bias + res_bf16
template <int MODE, int TN>
__global__ __launch_bounds__(256) void gemm_kernel(
    const u16* __restrict__ A, const u16* __restrict__ Bt,
    int M, int N, int K, int ldc,
    const float* __restrict__ bias, const void* __restrict__ res,
    void* __restrict__ out0, void* __restrict__ out1, void* __restrict__ out2,
    void* __restrict__ out3) {
  __shared__ u16 Als[2][128 * 32];
  __shared__ u16 Bls[2][TN * 32];
  const int NJ = TN / 32;  // N-frags per wave
  const int MB = M >> 7;
  int mb = blockIdx.x % MB, nb = blockIdx.x / MB;
  int m0 = mb << 7, n0 = nb * TN;
  int tid = threadIdx.x;
  int lane = tid & 63, w = tid >> 6;
  int wm = (w >> 1) << 6, wn = (w & 1) * (TN / 2);
  int l15 = lane & 15, l16 = lane >> 4;
  const f32x4 fz = {0.f, 0.f, 0.f, 0.f};
  f32x4 acc[4][NJ];
#pragma unroll
  for (int i = 0; i < 4; i++)
#pragma unroll
    for (int j = 0; j < NJ; j++) acc[i][j] = fz;

  // staging: lane l -> row +(l>>2), chunk (l&3)*8; one GLD16 covers 16 rows
  const int strow = lane >> 2, stch = (lane & 3) * 8;
  const u16* Ag = A + (size_t)(m0 + w * 32 + strow) * K + stch;
  const u16* Bg = Bt + (size_t)(n0 + w * (TN / 4) + strow) * K + stch;
  u16* Al0 = &Als[0][(w * 32) * 32];
  u16* Al1 = &Als[1][(w * 32) * 32];
  u16* Bl0 = &Bls[0][(w * (TN / 4)) * 32];
  u16* Bl1 = &Bls[1][(w * (TN / 4)) * 32];

  for (int k0 = 0; k0 < K; k0 += 64) {
    __syncthreads();  // prev tile's ds_reads done
    GLD16(Ag + k0, Al0);
    GLD16(Ag + k0 + (size_t)16 * K, Al0 + 16 * 32);
    GLD16(Ag + k0 + 32, Al1);
    GLD16(Ag + k0 + 32 + (size_t)16 * K, Al1 + 16 * 32);
    GLD16(Bg + k0, Bl0);
    GLD16(Bg + k0 + 32, Bl1);
    if (TN == 128) {
      GLD16(Bg + k0 + (size_t)16 * K, Bl0 + 16 * 32);
      GLD16(Bg + k0 + 32 + (size_t)16 * K, Bl1 + 16 * 32);
    }
    asm volatile("s_waitcnt vmcnt(0)" ::: "memory");  // drain LDS-DMA before barrier
    __syncthreads();
#pragma unroll
    for (int kk = 0; kk < 2; kk++) {
      short8 af[4], bfr[NJ];
#pragma unroll
      for (int i = 0; i < 4; i++)
        af[i] = *(const short8*)&Als[kk][(wm + i * 16 + l15) * 32 + l16 * 8];
#pragma unroll
      for (int j = 0; j < NJ; j++)
        bfr[j] = *(const short8*)&Bls[kk][(wn + j * 16 + l15) * 32 + l16 * 8];
      __builtin_amdgcn_s_setprio(1);
#pragma unroll
      for (int i = 0; i < 4; i++)
#pragma unroll
        for (int j = 0; j < NJ; j++)
          acc[i][j] = __builtin_amdgcn_mfma_f32_16x16x32_bf16(af[i], bfr[j], acc[i][j], 0, 0, 0);
      __builtin_amdgcn_s_setprio(0);
    }
  }

#pragma unroll
  for (int i = 0; i < 4; i++)
#pragma unroll
    for (int j = 0; j < NJ; j++)
#pragma unroll
      for (int r = 0; r < 4; r++) {
        int row = m0 + wm + i * 16 + l16 * 4 + r;
        int col = n0 + wn + j * 16 + l15;
        float v = acc[i][j][r];
        if (MODE == 1) {
          ((u16*)out0)[(size_t)row * ldc + col] = f2bf(v + bias[col]);
        } else if (MODE == 2) {
          if (col < 384) {
            ((u16*)out0)[(size_t)row * 384 + col] = f2bf(v * 0.18033688011112042f);
          } else if (col < 768) {
            ((u16*)out1)[(size_t)row * 384 + col - 384] = f2bf(v);
          } else if (col < 1152) {
            int df = col - 768, hh = df >> 6, dd = df & 63;
            ((u16*)out2)[(((size_t)(row >> 11) * 6 + hh) * 64 + dd) * 2048 + (row & 2047)] = f2bf(v);
          } else {
            ((u16*)out3)[(size_t)row * 768 + (col - 1152)] = f2bf(v);
          }
        } else if (MODE == 4) {
          float u = v + bias[col];
          // tanh-form GELU via exp2 (max dev from erf-GELU ~3e-4, threshold 0.115)
          float t = u * (0.79788456f + 0.03567741f * u * u);
          float g = u / (1.f + exp2f(-2.88539008f * t));
          ((u16*)out0)[(size_t)row * ldc + col] = f2bf(g);
        } else if (MODE == 5) {
          float rv = ((const float*)res)[(size_t)row * ldc + col];
          ((u16*)out0)[(size_t)row * ldc + col] = f2bf(v + bias[col] + rv);
        } else if (MODE == 6) {
          float rv = b2f(((const u16*)res)[(size_t)row * ldc + col]);
          ((float*)out0)[(size_t)row * ldc + col] = v + bias[col] + rv;
        }
      }
}

// ---------------- flash attention (R14/R16 proven best) + T1 XCD-grouping:
// bijective remap work=(bx&7)*96+(bx>>3) puts all 16 blocks of one (b,h) — sharing a
// 512KB K/V slice — on ONE XCD's L2 (6 groups x 512KB = 3MB < 4MB). 8-wave blocks
// (128 q-rows), stride-80 LDS, swapped QK^T, shift-free softmax, ones-MFMA row-sum.
#define ASTR 80  // LDS row stride in u16 (160 B): 4-way max read conflicts, 16B-aligned
__global__ __launch_bounds__(512) void attn_kernel(const u16* __restrict__ qb,
                                                   const u16* __restrict__ kb,
                                                   const u16* __restrict__ vtb,
                                                   u16* __restrict__ ab) {
  __shared__ u16 Kls[64 * ASTR];
  __shared__ u16 Vls[64 * ASTR];    // [d][j] (V pre-transposed in global)
  __shared__ u16 Pls[128 * ASTR];   // Q staging (128 rows), then P[q][key] per-wave rows
  int bx0 = blockIdx.x;
  int bx = (bx0 & 7) * 96 + (bx0 >> 3);  // XCD-group swizzle (768 = 8*96, bijective)
  int q0 = (bx & 15) << 7;
  int h = (bx >> 4) % 6;
  int b = bx / 96;
  int tid = threadIdx.x, lane = tid & 63, w = tid >> 6;  // w in 0..7
  int l15 = lane & 15, l16 = lane >> 4;

  // stage Q (128 rows x 64 cols) into Pls; each wave then reads only its own 16 rows
  const size_t qbase = (size_t)(b * 2048 + q0) * 384 + h * 64;
  {
    int i0 = tid, i1 = 512 + tid;
    *(short8*)&Pls[(i0 >> 3) * ASTR + (i0 & 7) * 8] =
        *(const short8*)&qb[qbase + (size_t)(i0 >> 3) * 384 + (i0 & 7) * 8];
    *(short8*)&Pls[(i1 >> 3) * ASTR + (i1 & 7) * 8] =
        *(const short8*)&qb[qbase + (size_t)(i1 >> 3) * 384 + (i1 & 7) * 8];
  }
  __syncthreads();
  short8 aq0 = *(const short8*)&Pls[(w * 16 + l15) * ASTR + l16 * 8];
  short8 aq1 = *(const short8*)&Pls[(w * 16 + l15) * ASTR + 32 + l16 * 8];

  const f32x4 fz = {0.f, 0.f, 0.f, 0.f};
  f32x4 ot[4];   // O^T: lane q = l15; d = di*16 + l16*4 + r
  f32x4 osum;    // P row-sum via ones-MFMA; every element = full sum for q=l15
#pragma unroll
  for (int di = 0; di < 4; di++) ot[di] = fz;
  osum = fz;
  short8 ones8;  // constant all-ones bf16 A-fragment (1.0 = 0x3F80)
#pragma unroll
  for (int i = 0; i < 8; i++) ones8[i] = (short)0x3F80;

  const size_t kbase = (size_t)b * 2048 * 384 + h * 64;
  const size_t vbase = ((size_t)b * 6 + h) * 64 * 2048;
  // staging: 64 rows x 64 cols = 512 short8 slots; 512 threads -> 1 slot each
  const int srow = tid >> 3, sch = (tid & 7) * 8;

  // preload tile 0 into regs (T14-lite)
  short8 kr = *(const short8*)&kb[kbase + (size_t)srow * 384 + sch];
  short8 vr = *(const short8*)&vtb[vbase + (size_t)srow * 2048 + sch];

  for (int t = 0; t < 32; t++) {
    __syncthreads();  // previous tile's LDS reads done (and Q-staging consumed)
    *(short8*)&Kls[srow * ASTR + sch] = kr;
    *(short8*)&Vls[srow * ASTR + sch] = vr;
    if (t + 1 < 32) {  // issue next tile's loads; they fly during compute below
      int j0n = (t + 1) << 6;
      kr = *(const short8*)&kb[kbase + (size_t)(j0n + srow) * 384 + sch];
      vr = *(const short8*)&vtb[vbase + (size_t)srow * 2048 + j0n + sch];
    }
    __syncthreads();

    // S^T = K·Q^T : mfma(A=K_frag, B=Q_frag) -> col=q=l15, row=key
    f32x4 s[4];
    __builtin_amdgcn_s_setprio(1);
#pragma unroll
    for (int nj = 0; nj < 4; nj++) {
      short8 kf0 = *(const short8*)&Kls[(nj * 16 + l15) * ASTR + l16 * 8];
      short8 kf1 = *(const short8*)&Kls[(nj * 16 + l15) * ASTR + 32 + l16 * 8];
      s[nj] = __builtin_amdgcn_mfma_f32_16x16x32_bf16(kf0, aq0, fz, 0, 0, 0);
      s[nj] = __builtin_amdgcn_mfma_f32_16x16x32_bf16(kf1, aq1, s[nj], 0, 0, 0);
    }
    __builtin_amdgcn_s_setprio(0);

    // shift-free softmax numerator: P = exp2(s) directly (bounded, no sub needed)
#pragma unroll
    for (int nj = 0; nj < 4; nj++) {
      float p0 = exp2f(s[nj][0]);
      float p1 = exp2f(s[nj][1]);
      float p2 = exp2f(s[nj][2]);
      float p3 = exp2f(s[nj][3]);
      // truncate-pack to bf16 pairs (scale-invariant rel err < 0.4%)
      u32 lo = (__float_as_uint(p1) & 0xffff0000u) | (__float_as_uint(p0) >> 16);
      u32 hi = (__float_as_uint(p3) & 0xffff0000u) | (__float_as_uint(p2) >> 16);
      u32x2 pr = {lo, hi};
      *(u32x2*)&Pls[(w * 16 + l15) * ASTR + nj * 16 + l16 * 4] = pr;
    }

    // O^T += V^T · P^T ; row-sum += ones · P^T (same B-frag, free normalizer)
    __builtin_amdgcn_s_setprio(1);
#pragma unroll
    for (int ks = 0; ks < 2; ks++) {
      short8 pb = *(const short8*)&Pls[(w * 16 + l15) * ASTR + ks * 32 + l16 * 8];
      osum = __builtin_amdgcn_mfma_f32_16x16x32_bf16(ones8, pb, osum, 0, 0, 0);
#pragma unroll
      for (int di = 0; di < 4; di++) {
        short8 vf = *(const short8*)&Vls[(di * 16 + l15) * ASTR + ks * 32 + l16 * 8];
        ot[di] = __builtin_amdgcn_mfma_f32_16x16x32_bf16(vf, pb, ot[di], 0, 0, 0);
      }
    }
    __builtin_amdgcn_s_setprio(0);
  }

  // osum[r] is the full P row-sum for q=l15 (replicated) — no reduce needed
  float inv = 1.f / osum[0];
  int token = b * 2048 + q0 + w * 16 + l15;
#pragma unroll
  for (int di = 0; di < 4; di++) {
    u16x4 pk4 = {f2bf(ot[di][0] * inv), f2bf(ot[di][1] * inv),
                 f2bf(ot[di][2] * inv), f2bf(ot[di][3] * inv)};
    *(u16x4*)&ab[(size_t)token * 384 + h * 64 + di * 16 + l16 * 4] = pk4;
  }
}

// ---------------- KNN (bf16 GH): u = G[idx] + (H[n]-G[n]+b); max over 8; leaky
// 8 bf16 per thread (one short8 gather per neighbor; idx loads halved)
__global__ void knn_kernel(const u16* __restrict__ GH, const int* __restrict__ kidx,
                           const float* __restrict__ kbias, u16* __restrict__ cat) {
  int f = blockIdx.x * 256 + threadIdx.x;
  if (f >= 16384 * 48) return;
  int token = f / 48, j8 = f - token * 48;
  int b = token >> 11, n = token & 2047;
  int j = j8 * 8;
  u16x8 gs = *(const u16x8*)&GH[(size_t)token * 768 + j];
  u16x8 hs = *(const u16x8*)&GH[(size_t)token * 768 + 384 + j];
  float d[8], m[8];
#pragma unroll
  for (int e = 0; e < 8; e++) {
    d[e] = b2f(hs[e]) - b2f(gs[e]) + kbias[j + e];
    m[e] = -1e30f;
  }
#pragma unroll
  for (int k = 0; k < 8; k++) {
    int t = kidx[(b * 8 + k) * 2048 + n];
    u16x8 g = *(const u16x8*)&GH[(size_t)t * 768 + j];
#pragma unroll
    for (int e = 0; e < 8; e++) m[e] = fmaxf(m[e], b2f(g[e]) + d[e]);
  }
  u16x8 pk;
#pragma unroll
  for (int e = 0; e < 8; e++) {
    float v = m[e] > 0.f ? m[e] : 0.2f * m[e];
    pk[e] = f2bf(v);
  }
  *(u16x8*)&cat[(size_t)token * 768 + 384 + j] = pk;
}

// ---------------- launch
extern "C" void kernel_launch(void* const* d_in, const int* in_sizes, int n_in,
                              void* d_out, int out_size, void* d_ws, size_t ws_size,
                              hipStream_t stream) {
  const float* x       = (const float*)d_in[0];
  const int*   kidx    = (const int*)d_in[1];
  const float* n1w     = (const float*)d_in[2];
  const float* n1b     = (const float*)d_in[3];
  const float* qkv_w   = (const float*)d_in[4];
  const float* proj_w  = (const float*)d_in[5];
  const float* proj_b  = (const float*)d_in[6];
  const float* knn_w   = (const float*)d_in[7];
  const float* knn_b   = (const float*)d_in[8];
  const float* merge_w = (const float*)d_in[9];
  const float* merge_b = (const float*)d_in[10];
  const float* n2w     = (const float*)d_in[11];
  const float* n2b     = (const float*)d_in[12];
  const float* fc1_w   = (const float*)d_in[13];
  const float* fc1_b   = (const float*)d_in[14];
  const float* fc2_w   = (const float*)d_in[15];
  const float* fc2_b   = (const float*)d_in[16];
  float* out = (float*)d_out;
  char* ws = (char*)d_ws;

  // ws layout (bytes)
  u16* wbig   = (u16*)(ws + 0);          // 1920x384 bf16: [qkv | knnW1 | knnW2]
  u16* wproj  = (u16*)(ws + 1474560);    // 384x384
  u16* wmerge = (u16*)(ws + 1769472);    // 384x768
  u16* wfc1   = (u16*)(ws + 2359296);    // 1536x384
  u16* wfc2   = (u16*)(ws + 3538944);    // 384x1536
  u16* nx     = (u16*)(ws + 4718592);    // norm_x bf16; later attn-out
  u16* qbf    = (u16*)(ws + 17301504);   // q (pre-scaled); later norm2 out
  u16* kbf    = (u16*)(ws + 29884416);   // k; later cat (spans k+vT)
  u16* vtb    = (u16*)(ws + 42467328);   // v transposed [b][h][d][n]
  u16* GH     = (u16*)(ws + 55050240);   // [16384][768] bf16; later h bf16
  u16* xmid   = (u16*)(ws + 105381888);  // [16384][384] bf16
  u16* cat = kbf;
  u16* n2  = qbf;
  u16* abf = nx;
  u16* hbf = GH;

  // merged weight transposes (7 jobs, 9216 blocks)
  TJobs J;
  J.in[0] = qkv_w;   J.outoff[0] = 0;       J.ld[0] = 1152; J.row0[0] = 0;   J.K[0] = 384;  J.blkend[0] = 1728;
  J.in[1] = knn_w;   J.outoff[1] = 884736;  J.ld[1] = 384;  J.row0[1] = 0;   J.K[1] = 384;  J.blkend[1] = 2304;
  J.in[2] = knn_w;   J.outoff[2] = 1179648; J.ld[2] = 384;  J.row0[2] = 384; J.K[2] = 384;  J.blkend[2] = 2880;
  J.in[3] = proj_w;  J.outoff[3] = 1474560; J.ld[3] = 384;  J.row0[3] = 0;   J.K[3] = 384;  J.blkend[3] = 3456;
  J.in[4] = merge_w; J.outoff[4] = 1769472; J.ld[4] = 384;  J.row0[4] = 0;   J.K[4] = 768;  J.blkend[4] = 4608;
  J.in[5] = fc1_w;   J.outoff[5] = 2359296; J.ld[5] = 1536; J.row0[5] = 0;   J.K[5] = 384;  J.blkend[5] = 6912;
  J.in[6] = fc2_w;   J.outoff[6] = 3538944; J.ld[6] = 384;  J.row0[6] = 0;   J.K[6] = 1536; J.blkend[6] = 9216;
  transpose_all_kernel<<<9216, 256, 0, stream>>>(J, ws);

  // LN1
  ln_kernel<<<16384, 64, 0, stream>>>(x, n1w, n1b, nx);
  // merged qkv+GH (split epilogue: q scaled, v transposed, GH bf16)
  gemm_kernel<2, 128><<<128 * 15, 256, 0, stream>>>(nx, wbig, 16384, 1920, 384, 0, nullptr, nullptr, qbf, kbf, vtb, GH);
  // attention -> abf (reuses nx space AFTER nx consumed); 8-wave blocks, grid 768
  attn_kernel<<<768, 512, 0, stream>>>(qbf, kbf, vtb, abf);
  // knn gather+max -> cat cols 384:768 (reuses k/v space AFTER attention)
  knn_kernel<<<3072, 256, 0, stream>>>(GH, kidx, knn_b, cat);
  // proj -> cat cols 0:384
  gemm_kernel<1, 64><<<128 * 6, 256, 0, stream>>>(abf, wproj, 16384, 384, 384, 768, proj_b, nullptr, cat, nullptr, nullptr, nullptr);
  // merge + f32 residual -> xmid (bf16)
  gemm_kernel<5, 64><<<128 * 6, 256, 0, stream>>>(cat, wmerge, 16384, 384, 768, 384, merge_b, x, xmid, nullptr, nullptr, nullptr);
  // LN2 (bf16 in)
  ln_bf16_kernel<<<16384, 64, 0, stream>>>(xmid, n2w, n2b, n2);
  // fc1 + gelu -> h (TN=64: 3072 blocks, 6 resident/CU, no occupancy tail)
  gemm_kernel<4, 64><<<128 * 24, 256, 0, stream>>>(n2, wfc1, 16384, 1536, 384, 1536, fc1_b, nullptr, hbf, nullptr, nullptr, nullptr);
  // fc2 + bf16 residual -> out (f32)
  gemm_kernel<6, 64><<<128 * 6, 256, 0, stream>>>(hbf, wfc2, 16384, 384, 1536, 384, fc2_b, xmid, out, nullptr, nullptr, nullptr);
}